// Round 2
// baseline (114.174 us; speedup 1.0000x reference)
//
#include <hip/hip_runtime.h>
#include <math.h>

#define BATCH 64
#define TLEN 2048
#define DIM 80
#define DQ (DIM / 4)           // 20 float4-quads per row
#define TCH 64                 // t-rows per block chunk
#define NCH (TLEN / TCH)       // 32 chunks per batch element
#define TT 4                   // rows per thread strip (16 strips x 4 = 64 rows)
#define THREADS 320            // 16 row-strips x 20 quads, 5 waves -> zero raggedness
#define NBLOCKS (BATCH * NCH)  // 2048 -> 8 blocks/CU ideal residency

// Smooth-min: K=32; c = K*log2(e)
#define SMIN_C  46.166241308446828f
#define SMIN_RC 0.02166084939249829f   // 1/c

// LESSON (R3-R5): same-cache-line device atomicAdd from all block leaders
// serializes cross-XCD (~+45 us tail). Plain per-block store + trailing
// 1-block reduce wins. LESSON (R4): forcing waves/EU via __launch_bounds__
// 2nd arg spills to scratch; leave VGPR to the compiler.
// LESSON (R8): 128-thr blocks cut resident waves 32->20 /CU for zero gain --
// the kernel is latency-bound; never trade TLP for "tail elimination".
// R9: LDS-stage the tgt tile. Kills (a) 2-scalar-per-row halo scatter loads
// (~17 cache lines per wave instr), (b) 1.5x tgt re-read, (c) ragged mapping.
// Staging span [t0-1, t0+64] is contiguous in memory -> pure float4 copy.

__device__ __forceinline__ float elem_loss(float x, const float* rm, const float* r0,
                                           const float* rp, int e) {
    float v[9];
#pragma unroll
    for (int i = 0; i < 3; ++i) {
        v[0 + i] = fabsf(x - rm[e + i]);
        v[3 + i] = fabsf(x - r0[e + i]);
        v[6 + i] = fabsf(x - rp[e + i]);
    }
    const float center = v[4];
    // min3-shaped tree: 4x v_min3_f32 (abs mods fold into VOP3 inputs)
    const float m0 = fminf(fminf(v[0], v[1]), v[2]);
    const float m1 = fminf(fminf(v[3], v[4]), v[5]);
    const float m2 = fminf(fminf(v[6], v[7]), v[8]);
    const float m  = fminf(fminf(m0, m1), m2);
    const float cm = SMIN_C * m;
    float ex[9];
#pragma unroll
    for (int s = 0; s < 9; ++s)
        ex[s] = __builtin_amdgcn_exp2f(fmaf(-SMIN_C, v[s], cm));   // args <= 0; S in [1,9]
    const float S = ((ex[0] + ex[1]) + (ex[2] + ex[3]))
                  + (((ex[4] + ex[5]) + (ex[6] + ex[7])) + ex[8]); // pairwise: ILP
    return center + m - __builtin_amdgcn_logf(S) * SMIN_RC;        // logf builtin = log2
}

__global__ __launch_bounds__(THREADS) void jitter_kernel(
    const float* __restrict__ inp, const float* __restrict__ tgt,
    float* __restrict__ ws)
{
    // sm row r holds tgt global row (t0 - 1 + r); rows 0 / TCH+1 may be zero pads
    __shared__ __align__(16) float sm[(TCH + 2) * DIM];   // 66*80*4 = 21120 B
    __shared__ float wsum[THREADS / 64];

    const int tc  = blockIdx.x & (NCH - 1);
    const int b   = blockIdx.x >> 5;           // / NCH
    const int t0  = tc * TCH;
    const int tid = threadIdx.x;

    // ---- stage tgt rows [t0-1, t0+TCH] (clamped) as one linear span ----
    const int sr = (tc == 0)       ? 1   : 0;        // first valid sm row
    const int er = (tc == NCH - 1) ? TCH : TCH + 1;  // last valid sm row
    const int nf = (er - sr + 1) * DIM;              // floats to copy (5200 or 5280)
    const float* gsrc = tgt + ((size_t)b * TLEN + (t0 - 1 + sr)) * DIM;
    float* sdst = sm + sr * DIM;
    for (int i = tid * 4; i < nf; i += THREADS * 4)
        *(float4*)(sdst + i) = *(const float4*)(gsrc + i);
    if (tc == 0 && tid < DIM / 4)
        *(float4*)(sm + tid * 4) = make_float4(0.f, 0.f, 0.f, 0.f);
    if (tc == NCH - 1 && tid < DIM / 4)
        *(float4*)(sm + (TCH + 1) * DIM + tid * 4) = make_float4(0.f, 0.f, 0.f, 0.f);
    __syncthreads();

    const int q  = tid % DQ;     // 0..19  quad within row
    const int rs = tid / DQ;     // 0..15  row-strip
    const int d0 = q * 4;

    const float* inb = inp + ((size_t)b * TLEN + t0 + rs * TT) * DIM + d0;

    // rolling 6-float windows out of LDS; global row g -> sm row g - t0 + 1
    float rm[6], r0[6], rp[6];
    {
        const float* p0 = sm + (rs * TT) * DIM + d0;       // row above strip
        const float* p1 = p0 + DIM;
        rm[0] = (q > 0) ? p0[-1] : 0.f;
        rm[1] = p0[0]; rm[2] = p0[1]; rm[3] = p0[2]; rm[4] = p0[3];
        rm[5] = (q < DQ - 1) ? p0[4] : 0.f;
        r0[0] = (q > 0) ? p1[-1] : 0.f;
        r0[1] = p1[0]; r0[2] = p1[1]; r0[3] = p1[2]; r0[4] = p1[3];
        r0[5] = (q < DQ - 1) ? p1[4] : 0.f;
    }

    float acc = 0.f;
#pragma unroll
    for (int lt = 0; lt < TT; ++lt) {
        const float* pp = sm + (rs * TT + lt + 2) * DIM + d0;
        rp[0] = (q > 0) ? pp[-1] : 0.f;
        const float4 v = *(const float4*)pp;
        rp[1] = v.x; rp[2] = v.y; rp[3] = v.z; rp[4] = v.w;
        rp[5] = (q < DQ - 1) ? pp[4] : 0.f;

        const float4 in4 = *(const float4*)(inb + (size_t)lt * DIM);
        acc += elem_loss(in4.x, rm, r0, rp, 0);
        acc += elem_loss(in4.y, rm, r0, rp, 1);
        acc += elem_loss(in4.z, rm, r0, rp, 2);
        acc += elem_loss(in4.w, rm, r0, rp, 3);
#pragma unroll
        for (int i = 0; i < 6; ++i) { rm[i] = r0[i]; r0[i] = rp[i]; }
    }

    // block reduction -> one plain store per block (no atomics, no contention)
#pragma unroll
    for (int off = 32; off > 0; off >>= 1)
        acc += __shfl_down(acc, off, 64);
    const int lane = tid & 63, wid = tid >> 6;
    if (lane == 0) wsum[wid] = acc;
    __syncthreads();
    if (tid == 0) {
        float tot = 0.f;
#pragma unroll
        for (int w = 0; w < THREADS / 64; ++w) tot += wsum[w];
        ws[blockIdx.x] = tot;
    }
}

__global__ __launch_bounds__(256) void reduce_kernel(const float* __restrict__ ws,
                                                     float* __restrict__ out) {
    __shared__ float wsum[4];
    float s = 0.f;
    for (int i = threadIdx.x; i < NBLOCKS; i += 256) s += ws[i];
#pragma unroll
    for (int off = 32; off > 0; off >>= 1)
        s += __shfl_down(s, off, 64);
    const int lane = threadIdx.x & 63, wid = threadIdx.x >> 6;
    if (lane == 0) wsum[wid] = s;
    __syncthreads();
    if (threadIdx.x == 0) {
        float tot = wsum[0] + wsum[1] + wsum[2] + wsum[3];
        out[0] = tot * (0.5f / (float)((size_t)BATCH * TLEN * DIM));
    }
}

extern "C" void kernel_launch(void* const* d_in, const int* in_sizes, int n_in,
                              void* d_out, int out_size, void* d_ws, size_t ws_size,
                              hipStream_t stream) {
    const float* inp = (const float*)d_in[0];
    const float* tgt = (const float*)d_in[1];
    float* ws  = (float*)d_ws;
    float* out = (float*)d_out;

    jitter_kernel<<<NBLOCKS, THREADS, 0, stream>>>(inp, tgt, ws);
    reduce_kernel<<<1, 256, 0, stream>>>(ws, out);
}